// Round 9
// baseline (316.889 us; speedup 1.0000x reference)
//
#include <hip/hip_runtime.h>
#include <cstdint>
#include <cstddef>

// ---------------------------------------------------------------------------
// MultiheadAttention (double-softmax variant), MI355X. B=4,S=1024,D=1024,H=16.
// Inputs FP32 (dict order: Q K V Wq bq Wk bk Wv bv Wo bo ln_g ln_b).
// OUTPUT FP32 (out_size = 4M floats = 16 MB) — rounds 1-8 failed because the
// output was written as bf16 u16s (f32 view = misaligned field, absmax 7.25;
// round-8's u16 stomp of out[0] only touched f32[0]'s mantissa -> invisible).
//   K1 qkv_proj : q/k/v = X @ W^T + b (q pre-scaled 1/8) -> ws bf16 [B,S,D]
//   K2 attn     : two-pass double-softmax flash (MFMA)   -> ctx bf16, staged
//                 in d_out bytes [8MB,16MB) (dead before K4 overwrites)
//   K3 out_proj : ctx @ Wo^T + bo                        -> ws pre f32 [B,S,D]
//   K4 ln       : LayerNorm(pre + Q)*g + b               -> d_out f32 [0,16MB)
// ws (24 MB): qb[0,8) kb[8,16) vb[16,24); pre f32 aliases [0,16) (dead by K3).
// ---------------------------------------------------------------------------

typedef unsigned short ushort_t;
typedef __attribute__((ext_vector_type(8))) short bf16x8;     // MFMA A/B frag
typedef __attribute__((ext_vector_type(8))) unsigned short us8;
typedef __attribute__((ext_vector_type(4))) float f32x4;      // MFMA C/D frag

#define MFMA16(a, b, c) __builtin_amdgcn_mfma_f32_16x16x32_bf16((a), (b), (c), 0, 0, 0)

__device__ __forceinline__ float b2f(ushort_t u) {
  union { unsigned int i; float f; } x; x.i = ((unsigned int)u) << 16; return x.f;
}
__device__ __forceinline__ ushort_t f2b(float f) {
  union { unsigned int i; float f; } x; x.f = f;
  unsigned int r = (x.i + 0x7FFFu + ((x.i >> 16) & 1u)) >> 16;  // RNE
  return (ushort_t)r;
}

// Load 8 consecutive elements: fp32 (f32flag=1) or bf16 (0); pack to bf16.
__device__ __forceinline__ us8 ld8(const void* base, size_t idx, int f32flag) {
  if (!f32flag) {
    return *(const us8*)((const ushort_t*)base + idx);
  }
  const float* f = (const float*)base + idx;
  const float4 a = *(const float4*)f;
  const float4 b = *(const float4*)(f + 4);
  us8 r;
  r[0] = f2b(a.x); r[1] = f2b(a.y); r[2] = f2b(a.z); r[3] = f2b(a.w);
  r[4] = f2b(b.x); r[5] = f2b(b.y); r[6] = f2b(b.z); r[7] = f2b(b.w);
  return r;
}

// ---------------------------------------------------------------------------
// 128x128 GEMM tile: C = A[m0:,:] * B[n0:,:]^T ; A:[MxK], B:[NxK].
// acc[ms][ns] elem r: row = wm+ms*16+quad*4+r, col = wn+ns*16+(lane&15).
// ---------------------------------------------------------------------------
__device__ __forceinline__ void gemm_tile(const void* __restrict__ A,
                                          const void* __restrict__ B,
                                          int K, int m0, int n0,
                                          int f32A, int f32B,
                                          ushort_t* Asl, ushort_t* Bsl,
                                          f32x4 acc[4][4]) {
  const int tid = threadIdx.x;
  const int wave = tid >> 6;
  const int lane = tid & 63;
  const int l15 = lane & 15;
  const int quad = lane >> 4;
  const int wm = (wave & 1) * 64;
  const int wn = (wave >> 1) * 64;

  for (int k0 = 0; k0 < K; k0 += 32) {
    __syncthreads();
#pragma unroll
    for (int c0 = 0; c0 < 512; c0 += 256) {
      const int c = c0 + tid;
      const int row = c >> 2, col = (c & 3) * 8;
      *(us8*)(Asl + row * 32 + col) = ld8(A, (size_t)(m0 + row) * K + (k0 + col), f32A);
      *(us8*)(Bsl + row * 32 + col) = ld8(B, (size_t)(n0 + row) * K + (k0 + col), f32B);
    }
    __syncthreads();
    bf16x8 af[4], bfr[4];
#pragma unroll
    for (int s = 0; s < 4; ++s) {
      af[s]  = *(const bf16x8*)(Asl + (wm + s * 16 + l15) * 32 + quad * 8);
      bfr[s] = *(const bf16x8*)(Bsl + (wn + s * 16 + l15) * 32 + quad * 8);
    }
#pragma unroll
    for (int ms = 0; ms < 4; ++ms)
#pragma unroll
      for (int ns = 0; ns < 4; ++ns)
        acc[ms][ns] = MFMA16(af[ms], bfr[ns], acc[ms][ns]);
  }
}

// ---------------------------------------------------------------------------
// K1: Q/K/V projections (blockIdx.z selects). fp32 in, bf16 [B,S,D] out.
// ---------------------------------------------------------------------------
__global__ __launch_bounds__(256, 2) void qkv_proj_kernel(
    const float* __restrict__ Qin, const float* __restrict__ Kin,
    const float* __restrict__ Vin,
    const float* __restrict__ Wq, const float* __restrict__ Wk,
    const float* __restrict__ Wv,
    const float* __restrict__ bq, const float* __restrict__ bk,
    const float* __restrict__ bv,
    ushort_t* __restrict__ qb, ushort_t* __restrict__ kb,
    ushort_t* __restrict__ vb) {
  __shared__ __align__(16) ushort_t Asl[128 * 32];
  __shared__ __align__(16) ushort_t Bsl[128 * 32];
  const float* A; const float* B; const float* bias; ushort_t* outp; float scale;
  if (blockIdx.z == 0)      { A = Qin; B = Wq; bias = bq; outp = qb; scale = 0.125f; }
  else if (blockIdx.z == 1) { A = Kin; B = Wk; bias = bk; outp = kb; scale = 1.0f; }
  else                      { A = Vin; B = Wv; bias = bv; outp = vb; scale = 1.0f; }
  const int m0 = blockIdx.y * 128, n0 = blockIdx.x * 128;
  f32x4 acc[4][4] = {};
  gemm_tile(A, B, 1024, m0, n0, 1, 1, Asl, Bsl, acc);

  const int lane = threadIdx.x & 63, wave = threadIdx.x >> 6;
  const int l15 = lane & 15, quad = lane >> 4;
  const int wm = (wave & 1) * 64, wn = (wave >> 1) * 64;
#pragma unroll
  for (int ns = 0; ns < 4; ++ns) {
    const int col = n0 + wn + ns * 16 + l15;
    const float bv_ = bias[col];
#pragma unroll
    for (int ms = 0; ms < 4; ++ms) {
      const int rowb = m0 + wm + ms * 16 + quad * 4;
#pragma unroll
      for (int r = 0; r < 4; ++r) {
        outp[(size_t)(rowb + r) * 1024 + col] =
            f2b((acc[ms][ns][r] + bv_) * scale);
      }
    }
  }
}

// ---------------------------------------------------------------------------
// K2: attention, double softmax, two passes over K/V tiles.
// Block: 4 waves, 64 q-rows of one (b,h). grid (16 q-tiles, 64 bh).
// ---------------------------------------------------------------------------
__global__ __launch_bounds__(256, 2) void attn_kernel(
    const ushort_t* __restrict__ qb, const ushort_t* __restrict__ kb,
    const ushort_t* __restrict__ vb, ushort_t* __restrict__ ctx) {
  __shared__ __align__(16) ushort_t Qs[64 * 72];      // [qrow][dk], stride 72
  __shared__ __align__(16) ushort_t Ks[64 * 72];      // [krow][dk]
  __shared__ __align__(16) ushort_t Vt[64 * 72];      // [d][krow]
  __shared__ __align__(16) ushort_t Ps[4][16 * 72];   // per-wave P [qrow][kcol]

  const int tid = threadIdx.x, wave = tid >> 6, lane = tid & 63;
  const int l15 = lane & 15, quad = lane >> 4;
  const int bh = blockIdx.y;
  const int b = bh >> 4, h = bh & 15;
  const int q0 = blockIdx.x * 64;
  const ushort_t* qg = qb + ((size_t)b << 20) + h * 64;
  const ushort_t* kg = kb + ((size_t)b << 20) + h * 64;
  const ushort_t* vg = vb + ((size_t)b << 20) + h * 64;

  // stage Q tile once: 64x64 = 512 us8 chunks
#pragma unroll
  for (int c0 = 0; c0 < 512; c0 += 256) {
    const int c = c0 + tid;
    const int row = c >> 3, col = (c & 7) * 8;
    *(us8*)(Qs + row * 72 + col) =
        *(const us8*)(qg + (size_t)(q0 + row) * 1024 + col);
  }

  float m1[4], l1[4];
#pragma unroll
  for (int r = 0; r < 4; ++r) { m1[r] = -1e30f; l1[r] = 0.0f; }

  // ---- pass 1: online (m1, Z1) over scores ----
  for (int kt = 0; kt < 16; ++kt) {
    __syncthreads();
#pragma unroll
    for (int c0 = 0; c0 < 512; c0 += 256) {
      const int c = c0 + tid;
      const int row = c >> 3, col = (c & 7) * 8;
      *(us8*)(Ks + row * 72 + col) =
          *(const us8*)(kg + (size_t)(kt * 64 + row) * 1024 + col);
    }
    __syncthreads();
    f32x4 sc[4] = {};
#pragma unroll
    for (int kk = 0; kk < 2; ++kk) {
      const bf16x8 aq = *(const bf16x8*)(Qs + (wave * 16 + l15) * 72 + kk * 32 + quad * 8);
#pragma unroll
      for (int ns = 0; ns < 4; ++ns) {
        const bf16x8 bk_ = *(const bf16x8*)(Ks + (ns * 16 + l15) * 72 + kk * 32 + quad * 8);
        sc[ns] = MFMA16(aq, bk_, sc[ns]);
      }
    }
#pragma unroll
    for (int r = 0; r < 4; ++r) {
      float mx = fmaxf(fmaxf(sc[0][r], sc[1][r]), fmaxf(sc[2][r], sc[3][r]));
#pragma unroll
      for (int off = 1; off < 16; off <<= 1) mx = fmaxf(mx, __shfl_xor(mx, off, 64));
      const float mn = fmaxf(m1[r], mx);
      float sm = 0.0f;
#pragma unroll
      for (int ns = 0; ns < 4; ++ns) sm += __expf(sc[ns][r] - mn);
#pragma unroll
      for (int off = 1; off < 16; off <<= 1) sm += __shfl_xor(sm, off, 64);
      l1[r] = l1[r] * __expf(m1[r] - mn) + sm;
      m1[r] = mn;
    }
  }

  float iz1[4];
#pragma unroll
  for (int r = 0; r < 4; ++r) iz1[r] = 1.0f / l1[r];

  f32x4 oac[4] = {};
  float z2[4] = {0.f, 0.f, 0.f, 0.f};

  // ---- pass 2: e = exp(softmax1), accumulate Z2 and e*V ----
  for (int kt = 0; kt < 16; ++kt) {
    __syncthreads();
#pragma unroll
    for (int c0 = 0; c0 < 512; c0 += 256) {
      const int c = c0 + tid;
      const int row = c >> 3, col = (c & 7) * 8;
      *(us8*)(Ks + row * 72 + col) =
          *(const us8*)(kg + (size_t)(kt * 64 + row) * 1024 + col);
    }
    {  // stage V transposed: thread (d = tid&63, seg = tid>>6) gathers 16 krows
      const int d = tid & 63, seg = tid >> 6;
      us8 va, vb_;
#pragma unroll
      for (int j = 0; j < 8; ++j)
        va[j] = vg[(size_t)(kt * 64 + seg * 16 + j) * 1024 + d];
#pragma unroll
      for (int j = 0; j < 8; ++j)
        vb_[j] = vg[(size_t)(kt * 64 + seg * 16 + 8 + j) * 1024 + d];
      *(us8*)(Vt + d * 72 + seg * 16) = va;
      *(us8*)(Vt + d * 72 + seg * 16 + 8) = vb_;
    }
    __syncthreads();
    f32x4 sc[4] = {};
#pragma unroll
    for (int kk = 0; kk < 2; ++kk) {
      const bf16x8 aq = *(const bf16x8*)(Qs + (wave * 16 + l15) * 72 + kk * 32 + quad * 8);
#pragma unroll
      for (int ns = 0; ns < 4; ++ns) {
        const bf16x8 bk_ = *(const bf16x8*)(Ks + (ns * 16 + l15) * 72 + kk * 32 + quad * 8);
        sc[ns] = MFMA16(aq, bk_, sc[ns]);
      }
    }
#pragma unroll
    for (int ns = 0; ns < 4; ++ns)
#pragma unroll
      for (int r = 0; r < 4; ++r) {
        const float p1 = __expf(sc[ns][r] - m1[r]) * iz1[r];  // softmax1 in [0,1]
        const float e2 = __expf(p1);                          // softmax2 numerator
        z2[r] += e2;
        Ps[wave][(quad * 4 + r) * 72 + ns * 16 + l15] = f2b(e2);
      }
    __syncthreads();
#pragma unroll
    for (int kk = 0; kk < 2; ++kk) {
      const bf16x8 ap = *(const bf16x8*)(&Ps[wave][l15 * 72 + kk * 32 + quad * 8]);
#pragma unroll
      for (int ns2 = 0; ns2 < 4; ++ns2) {
        const bf16x8 bv_ = *(const bf16x8*)(Vt + (ns2 * 16 + l15) * 72 + kk * 32 + quad * 8);
        oac[ns2] = MFMA16(ap, bv_, oac[ns2]);
      }
    }
  }

#pragma unroll
  for (int r = 0; r < 4; ++r) {
    float s = z2[r];
#pragma unroll
    for (int off = 1; off < 16; off <<= 1) s += __shfl_xor(s, off, 64);
    z2[r] = s;
  }
#pragma unroll
  for (int ns2 = 0; ns2 < 4; ++ns2) {
    const int d = ns2 * 16 + l15;
#pragma unroll
    for (int r = 0; r < 4; ++r) {
      const int s = q0 + wave * 16 + quad * 4 + r;
      ctx[((size_t)(b * 1024 + s)) * 1024 + h * 64 + d] = f2b(oac[ns2][r] / z2[r]);
    }
  }
}

// ---------------------------------------------------------------------------
// K3: pre = ctx @ Wo^T + bo  (f32; residual deferred to K4)
// ---------------------------------------------------------------------------
__global__ __launch_bounds__(256, 2) void out_proj_kernel(
    const ushort_t* __restrict__ ctxp, const float* __restrict__ Wo,
    const float* __restrict__ bo, float* __restrict__ pre) {
  __shared__ __align__(16) ushort_t Asl[128 * 32];
  __shared__ __align__(16) ushort_t Bsl[128 * 32];
  const int m0 = blockIdx.y * 128, n0 = blockIdx.x * 128;
  f32x4 acc[4][4] = {};
  gemm_tile(ctxp, Wo, 1024, m0, n0, 0, 1, Asl, Bsl, acc);

  const int lane = threadIdx.x & 63, wave = threadIdx.x >> 6;
  const int l15 = lane & 15, quad = lane >> 4;
  const int wm = (wave & 1) * 64, wn = (wave >> 1) * 64;
#pragma unroll
  for (int ns = 0; ns < 4; ++ns) {
    const int col = n0 + wn + ns * 16 + l15;
    const float bv_ = bo[col];
#pragma unroll
    for (int ms = 0; ms < 4; ++ms) {
      const int rowb = m0 + wm + ms * 16 + quad * 4;
#pragma unroll
      for (int r = 0; r < 4; ++r) {
        const size_t i = (size_t)(rowb + r);
        pre[i * 1024 + col] = acc[ms][ns][r] + bv_;
      }
    }
  }
}

// ---------------------------------------------------------------------------
// K4: out = LayerNorm(pre + Q)*g + b -> FP32. One block (4 waves) per row.
// ---------------------------------------------------------------------------
__global__ __launch_bounds__(256, 4) void ln_kernel(
    const float* __restrict__ pre, const float* __restrict__ Q,
    const float* __restrict__ g, const float* __restrict__ bta,
    float* __restrict__ out) {
  const int row = blockIdx.x;
  const int tid = threadIdx.x;
  const size_t base = (size_t)row * 1024 + tid * 4;
  const float4 p4 = *(const float4*)(pre + base);
  const float4 q4 = *(const float4*)(Q + base);
  float v[4] = {p4.x + q4.x, p4.y + q4.y, p4.z + q4.z, p4.w + q4.w};
  float s1 = v[0] + v[1] + v[2] + v[3];
  float s2 = v[0]*v[0] + v[1]*v[1] + v[2]*v[2] + v[3]*v[3];
#pragma unroll
  for (int off = 1; off < 64; off <<= 1) {
    s1 += __shfl_xor(s1, off, 64);
    s2 += __shfl_xor(s2, off, 64);
  }
  __shared__ float r1[4], r2[4];
  const int wave = tid >> 6, lane = tid & 63;
  if (lane == 0) { r1[wave] = s1; r2[wave] = s2; }
  __syncthreads();
  const float t1 = r1[0] + r1[1] + r1[2] + r1[3];
  const float t2 = r2[0] + r2[1] + r2[2] + r2[3];
  const float mu = t1 * (1.0f / 1024.0f);
  const float var = t2 * (1.0f / 1024.0f) - mu * mu;
  const float inv = rsqrtf(var + 1e-5f);
  const int c0 = tid * 4;
#pragma unroll
  for (int j = 0; j < 4; ++j) {
    const int c = c0 + j;
    out[(size_t)row * 1024 + c] = (v[j] - mu) * inv * g[c] + bta[c];
  }
}

// ---------------------------------------------------------------------------
extern "C" void kernel_launch(void* const* d_in, const int* in_sizes, int n_in,
                              void* d_out, int out_size, void* d_ws, size_t ws_size,
                              hipStream_t stream) {
  const float* Q  = (const float*)d_in[0];
  const float* K  = (const float*)d_in[1];
  const float* V  = (const float*)d_in[2];
  const float* Wq = (const float*)d_in[3];
  const float* bq = (const float*)d_in[4];
  const float* Wk = (const float*)d_in[5];
  const float* bk = (const float*)d_in[6];
  const float* Wv = (const float*)d_in[7];
  const float* bv = (const float*)d_in[8];
  const float* Wo = (const float*)d_in[9];
  const float* bo = (const float*)d_in[10];
  const float* lg = (const float*)d_in[11];
  const float* lb = (const float*)d_in[12];

  char* ws = (char*)d_ws;                       // 24 MB used
  ushort_t* qb  = (ushort_t*)(ws);                         // bf16 [B,S,D], q scaled
  ushort_t* kb  = (ushort_t*)(ws + ((size_t)8  << 20));
  ushort_t* vb  = (ushort_t*)(ws + ((size_t)16 << 20));
  float*    pre = (float*)(ws);                 // f32, aliases qb+kb (dead by K3)
  // ctx (bf16, 8 MB) staged in the UPPER half of the 16 MB f32 output buffer;
  // K4 overwrites it only after K3 consumed it (stream-ordered).
  ushort_t* ctx = (ushort_t*)d_out + 4194304;
  float*    out = (float*)d_out;

  qkv_proj_kernel<<<dim3(8, 32, 3), 256, 0, stream>>>(Q, K, V, Wq, Wk, Wv,
                                                      bq, bk, bv, qb, kb, vb);
  attn_kernel<<<dim3(16, 64), 256, 0, stream>>>(qb, kb, vb, ctx);
  out_proj_kernel<<<dim3(8, 32), 256, 0, stream>>>(ctx, Wo, bo, pre);
  ln_kernel<<<dim3(4096), 256, 0, stream>>>(pre, Q, lg, lb, out);
}